// Round 5
// baseline (262.190 us; speedup 1.0000x reference)
//
#include <hip/hip_runtime.h>

// ---------------------------------------------------------------------------
// Head_87033217286245: Conv1d(1024->64,k=3) + span-softmax extractor + MLP
// Round 5: LDS-free conv GEMM. A-fragments loaded per-lane straight from
// global (fp32->f16 in registers), B prefetched from packed L2-hot array.
// 16 waves/CU (vs 8 in R1-R4: the shared 152us plateau was load-latency
// duty cycle at 2 waves/SIMD, not bandwidth).
// ---------------------------------------------------------------------------

typedef _Float16 f16x8 __attribute__((ext_vector_type(8)));
typedef float    f32x16 __attribute__((ext_vector_type(16)));

#define B_      128
#define L_      512
#define DBERT   1024
#define DPROJ   64
#define NSPANS  3
#define HIDDEN  512
#define KK      64            // k-steps of 16

// packed weights: f = kk*6 + t*2 + ch ; Bp[f*512 + lane*8 + j] =
//   W[o = ch*32 + (lane&31)][k = kk*16 + (lane>>5)*8 + j][t]
__global__ __launch_bounds__(256)
void pack_w_kernel(const float* __restrict__ Wc, _Float16* __restrict__ Bp) {
    int idx = blockIdx.x * 256 + threadIdx.x;          // 24576
    if (idx >= 384 * 64) return;
    int lane = idx & 63;
    int f    = idx >> 6;
    int ch   = f & 1;
    int t    = (f >> 1) % 3;
    int kk   = (f >> 1) / 3;
    int o     = ch * 32 + (lane & 31);
    int kbase = kk * 16 + ((lane >> 5) << 3);
    f16x8 v;
    #pragma unroll
    for (int j = 0; j < 8; ++j)
        v[j] = (_Float16)Wc[(size_t)o * (DBERT * 3) + (size_t)(kbase + j) * 3 + t];
    *(f16x8*)(Bp + (size_t)idx * 8) = v;
}

// 1024 blocks x 256 threads (4 waves), no LDS in loop -> 4 blocks/CU.
// Wave (rg=wv>>1, ch=wv&1): 32 rows x 32 cols, full K. Barrier-free loop.
__global__ __launch_bounds__(256, 4)
void conv_gemm_kernel(const float* __restrict__ X, const _Float16* __restrict__ Bp,
                      const float* __restrict__ cb, const float* __restrict__ aw,
                      const float* __restrict__ ab_p, const float* __restrict__ zp,
                      float* __restrict__ Y, float* __restrict__ Lg) {
    __shared__ float loglds[2][64];

    const int tid  = threadIdx.x;
    const int wv   = tid >> 6;
    const int lane = tid & 63;
    const int rg   = wv >> 1;
    const int ch   = wv & 1;
    const int m0   = blockIdx.x * 64;
    const int l0   = m0 & (L_ - 1);
    const int g0   = m0 - l0;
    const int r    = rg * 32 + (lane & 31);
    const int koct = (lane >> 5) << 3;

    // per-tap per-lane base pointers; OOB rows -> zero page (L1-hot)
    const float* ap[3];
    #pragma unroll
    for (int t = 0; t < 3; ++t) {
        int l = l0 + r + t - 1;
        ap[t] = (l >= 0 && l < L_) ? (X + (size_t)(g0 + l) * DBERT + koct)
                                   : (zp + koct);
    }
    const _Float16* bp = Bp + (size_t)ch * 512 + (size_t)lane * 8;

    // prefetch kk=0
    float4 a0[3][2], a1[3][2];
    f16x8  b0[3], b1[3];
    #pragma unroll
    for (int t = 0; t < 3; ++t) {
        a0[t][0] = *(const float4*)(ap[t]);
        a0[t][1] = *(const float4*)(ap[t] + 4);
        b0[t]    = *(const f16x8*)(bp + t * 1024);
    }

    f32x16 acc = {};
    #pragma unroll 2
    for (int kk = 0; kk < KK; ++kk) {
        if (kk + 1 < KK) {
            #pragma unroll
            for (int t = 0; t < 3; ++t) {
                const float* p = ap[t] + (kk + 1) * 16;
                a1[t][0] = *(const float4*)(p);
                a1[t][1] = *(const float4*)(p + 4);
                b1[t]    = *(const f16x8*)(bp + (size_t)(kk + 1) * 3072 + t * 1024);
            }
        }
        #pragma unroll
        for (int t = 0; t < 3; ++t) {
            f16x8 h;
            h[0] = (_Float16)a0[t][0].x; h[1] = (_Float16)a0[t][0].y;
            h[2] = (_Float16)a0[t][0].z; h[3] = (_Float16)a0[t][0].w;
            h[4] = (_Float16)a0[t][1].x; h[5] = (_Float16)a0[t][1].y;
            h[6] = (_Float16)a0[t][1].z; h[7] = (_Float16)a0[t][1].w;
            acc = __builtin_amdgcn_mfma_f32_32x32x16_f16(h, b0[t], acc, 0, 0, 0);
        }
        #pragma unroll
        for (int t = 0; t < 3; ++t) {
            a0[t][0] = a1[t][0]; a0[t][1] = a1[t][1]; b0[t] = b1[t];
        }
    }

    // ---- epilogue: bias + store Y + logit partials (C map verified in R4)
    const int   col = ch * 32 + (lane & 31);
    const float cbv = cb[col];
    const float awv = aw[col];
    const int rbase = (lane >> 5) << 2;
    #pragma unroll
    for (int i = 0; i < 16; ++i) {
        float c = acc[i] + cbv;
        int row = (i & 3) + 8 * (i >> 2) + rbase;        // 0..31 in rg tile
        Y[(size_t)(m0 + rg * 32 + row) * DPROJ + col] = c;
        float p = c * awv;
        p += __shfl_xor(p, 1);  p += __shfl_xor(p, 2);
        p += __shfl_xor(p, 4);  p += __shfl_xor(p, 8);
        p += __shfl_xor(p, 16);
        if ((lane & 31) == 0) loglds[ch][rg * 32 + row] = p;
    }
    __syncthreads();
    if (tid < 64)
        Lg[m0 + tid] = loglds[0][tid] + loglds[1][tid] + ab_p[0];
}

// one block per (batch, span): masked softmax over the span + weighted sum
__global__ __launch_bounds__(256)
void span_emb_kernel(const float* __restrict__ conv, const float* __restrict__ Lg,
                     const int* __restrict__ offs, float* __restrict__ emb) {
    __shared__ float logits[L_];
    __shared__ float red[8];
    __shared__ float part[256];

    const int bs   = blockIdx.x;               // 0..383
    const int b    = bs / NSPANS;
    const int sp   = bs - b * NSPANS;
    const int tid  = threadIdx.x;
    const int lane = tid & 63;
    const int wv   = tid >> 6;

    if (tid < 128)
        *(float4*)(&logits[tid * 4]) = *(const float4*)(Lg + (size_t)b * L_ + tid * 4);
    __syncthreads();

    const int st = offs[b * (NSPANS * 2) + sp * 2 + 0];
    const int en = offs[b * (NSPANS * 2) + sp * 2 + 1];      // inclusive

    float mx = -1e30f;
    for (int l = st + tid; l <= en; l += 256) mx = fmaxf(mx, logits[l]);
    #pragma unroll
    for (int off = 32; off >= 1; off >>= 1) mx = fmaxf(mx, __shfl_xor(mx, off));
    if (lane == 0) red[wv] = mx;
    __syncthreads();
    mx = fmaxf(fmaxf(red[0], red[1]), fmaxf(red[2], red[3]));
    __syncthreads();

    float sm = 0.f;
    for (int l = st + tid; l <= en; l += 256) sm += __expf(logits[l] - mx);
    #pragma unroll
    for (int off = 32; off >= 1; off >>= 1) sm += __shfl_xor(sm, off);
    if (lane == 0) red[wv] = sm;
    __syncthreads();
    const float denom = red[0] + red[1] + red[2] + red[3];

    float a = 0.f;
    for (int l = st + wv; l <= en; l += 4)
        a += __expf(logits[l] - mx) * conv[((size_t)b * L_ + l) * DPROJ + lane];
    part[tid] = a;
    __syncthreads();
    if (tid < DPROJ)
        emb[(size_t)bs * DPROJ + tid] =
            (part[tid] + part[64 + tid] + part[128 + tid] + part[192 + tid]) / denom;
}

// one block per batch: BN1 -> fc(192->512) -> ReLU -> BN2 -> concat -> last(529->3)
__global__ __launch_bounds__(256)
void span_fc_kernel(const float* __restrict__ emb_in,
                    const float* __restrict__ in_urls, const float* __restrict__ other,
                    const float* __restrict__ bn1_g, const float* __restrict__ bn1_b,
                    const float* __restrict__ bn1_m, const float* __restrict__ bn1_v,
                    const float* __restrict__ fc_w, const float* __restrict__ fc_b,
                    const float* __restrict__ bn2_g, const float* __restrict__ bn2_b,
                    const float* __restrict__ bn2_m, const float* __restrict__ bn2_v,
                    const float* __restrict__ last_w, const float* __restrict__ last_b,
                    float* __restrict__ out) {
    __shared__ float emb[NSPANS * DPROJ];
    __shared__ float hbuf[HIDDEN];

    const int b    = blockIdx.x;
    const int tid  = threadIdx.x;
    const int lane = tid & 63;
    const int wv   = tid >> 6;

    if (tid < NSPANS * DPROJ) {
        float e = emb_in[(size_t)b * (NSPANS * DPROJ) + tid];
        emb[tid] = (e - bn1_m[tid]) * rsqrtf(bn1_v[tid] + 1e-5f) * bn1_g[tid] + bn1_b[tid];
    }
    __syncthreads();

    #pragma unroll
    for (int q = 0; q < 2; ++q) {
        const int j = tid + q * 256;
        const float* wrow = fc_w + (size_t)j * (NSPANS * DPROJ);
        float s = fc_b[j];
        #pragma unroll 8
        for (int i = 0; i < NSPANS * DPROJ; ++i) s += wrow[i] * emb[i];
        s = fmaxf(s, 0.f);
        hbuf[j] = (s - bn2_m[j]) * rsqrtf(bn2_v[j] + 1e-5f) * bn2_g[j] + bn2_b[j];
    }
    __syncthreads();

    if (wv < 3) {
        const float* lw = last_w + wv * (HIDDEN + 17);
        float s = 0.f;
        for (int i = lane; i < HIDDEN + 17; i += 64) {
            float f;
            if (i < HIDDEN)          f = hbuf[i];
            else if (i < HIDDEN + 3) f = in_urls[b * 3 + (i - HIDDEN)];
            else                     f = other[b * 14 + (i - HIDDEN - 3)];
            s += lw[i] * f;
        }
        #pragma unroll
        for (int off = 32; off >= 1; off >>= 1) s += __shfl_xor(s, off);
        if (lane == 0) out[b * 3 + wv] = s + last_b[wv];
    }
}

extern "C" void kernel_launch(void* const* d_in, const int* in_sizes, int n_in,
                              void* d_out, int out_size, void* d_ws, size_t ws_size,
                              hipStream_t stream) {
    const float* bert    = (const float*)d_in[0];
    const int*   offs    = (const int*)d_in[1];
    const float* in_urls = (const float*)d_in[2];
    const float* other   = (const float*)d_in[3];
    const float* conv_w  = (const float*)d_in[4];
    const float* conv_b  = (const float*)d_in[5];
    const float* att_w   = (const float*)d_in[6];
    const float* att_b   = (const float*)d_in[7];
    const float* bn1_g   = (const float*)d_in[8];
    const float* bn1_b   = (const float*)d_in[9];
    const float* bn1_m   = (const float*)d_in[10];
    const float* bn1_v   = (const float*)d_in[11];
    const float* fc_w    = (const float*)d_in[12];
    const float* fc_b    = (const float*)d_in[13];
    const float* bn2_g   = (const float*)d_in[14];
    const float* bn2_b   = (const float*)d_in[15];
    const float* bn2_m   = (const float*)d_in[16];
    const float* bn2_v   = (const float*)d_in[17];
    const float* last_w  = (const float*)d_in[18];
    const float* last_b  = (const float*)d_in[19];

    // ws: Bp 384KB | convout 16.78MB | Lg 256KB | emb 96KB | zeros 4KB
    _Float16* Bp      = (_Float16*)d_ws;
    float*    convout = (float*)((char*)d_ws + 393216);
    float*    logits  = (float*)((char*)d_ws + 17170432);
    float*    emb     = (float*)((char*)d_ws + 17432576);
    float*    zeros   = (float*)((char*)d_ws + 17530880);

    hipMemsetAsync(zeros, 0, 4096, stream);
    hipLaunchKernelGGL(pack_w_kernel, dim3(96), dim3(256), 0, stream, conv_w, Bp);
    hipLaunchKernelGGL(conv_gemm_kernel, dim3((B_ * L_) / 64), dim3(256), 0, stream,
                       bert, Bp, conv_b, att_w, att_b, zeros, convout, logits);
    hipLaunchKernelGGL(span_emb_kernel, dim3(B_ * NSPANS), dim3(256), 0, stream,
                       convout, logits, offs, emb);
    hipLaunchKernelGGL(span_fc_kernel, dim3(B_), dim3(256), 0, stream,
                       emb, in_urls, other,
                       bn1_g, bn1_b, bn1_m, bn1_v, fc_w, fc_b,
                       bn2_g, bn2_b, bn2_m, bn2_v, last_w, last_b,
                       (float*)d_out);
}

// Round 6
// 223.082 us; speedup vs baseline: 1.1753x; 1.1753x over previous
//
#include <hip/hip_runtime.h>

// ---------------------------------------------------------------------------
// Head_87033217286245 — Round 6: algebraic restructure. The conv GEMM is never
// materialized. Using linearity:
//   logits[l] = X3[l,:]·(W·aw) + const          (pass 1: coalesced triple-dot)
//   span_emb[s,o] = (Sum_t,k W[o,k,t]·ybar_t[k])/Z + cb[o],
//     ybar_t[k] = Sum_l exp(logit[l]-mx)·X[l+t-1,k]   (pass 2: coalesced axpy)
// Both passes are pure streaming patterns (no MFMA, no LDS transpose) that
// saturate HBM; the R1-R5 fragment-transpose bottleneck is gone.
// ---------------------------------------------------------------------------

typedef float f32x4 __attribute__((ext_vector_type(4)));

#define B_      128
#define L_      512
#define DBERT   1024
#define NSPANS  3
#define HIDDEN  512

__device__ __forceinline__ float dp4(f32x4 a, f32x4 b) {
    return a.x*b.x + a.y*b.y + a.z*b.z + a.w*b.w;
}

// ---- k0: u_t[k] = Sum_o W[o,k,t]*aw[o]; Wt[t][o][k] = W[o][k][t] (contig k)
__global__ __launch_bounds__(256)
void prep_kernel(const float* __restrict__ cw, const float* __restrict__ aw,
                 float* __restrict__ u, float* __restrict__ Wt) {
    const int idx = blockIdx.x * 256 + threadIdx.x;      // 96*256 = 24576
    if (idx < 3072) {
        const int t = idx >> 10, k = idx & 1023;
        float s = 0.f;
        #pragma unroll 8
        for (int o = 0; o < 64; ++o)
            s += cw[(size_t)(o * 1024 + k) * 3 + t] * aw[o];
        u[idx] = s;
    }
    for (int i = idx; i < 196608; i += 96 * 256) {
        const int t = i >> 16, rest = i & 65535;
        const int o = rest >> 10, k = rest & 1023;
        Wt[i] = cw[(size_t)(o * 1024 + k) * 3 + t];
    }
}

// ---- k1: per global row m (0..65535): d_t[m] = X[m,:]·u_t. Wave per row,
// lane covers k = q*256 + lane*4 -> four fully-coalesced 1KB loads per row.
__global__ __launch_bounds__(256, 4)
void dots_kernel(const float* __restrict__ X, const float* __restrict__ u,
                 float* __restrict__ d0, float* __restrict__ d1,
                 float* __restrict__ d2) {
    const int tid = threadIdx.x, lane = tid & 63, wv = tid >> 6;
    f32x4 uu[3][4];
    #pragma unroll
    for (int t = 0; t < 3; ++t)
        #pragma unroll
        for (int q = 0; q < 4; ++q)
            uu[t][q] = *(const f32x4*)(u + t * 1024 + q * 256 + lane * 4);

    const int wrow0 = (blockIdx.x * 4 + wv) * 8;         // 2048 blocks
    const float* xp = X + (size_t)wrow0 * 1024 + lane * 4;
    #pragma unroll 2
    for (int i = 0; i < 8; ++i) {
        const float* rp = xp + (size_t)i * 1024;
        f32x4 x0 = *(const f32x4*)(rp);
        f32x4 x1 = *(const f32x4*)(rp + 256);
        f32x4 x2 = *(const f32x4*)(rp + 512);
        f32x4 x3 = *(const f32x4*)(rp + 768);
        float p0 = dp4(x0, uu[0][0]) + dp4(x1, uu[0][1]) + dp4(x2, uu[0][2]) + dp4(x3, uu[0][3]);
        float p1 = dp4(x0, uu[1][0]) + dp4(x1, uu[1][1]) + dp4(x2, uu[1][2]) + dp4(x3, uu[1][3]);
        float p2 = dp4(x0, uu[2][0]) + dp4(x1, uu[2][1]) + dp4(x2, uu[2][2]) + dp4(x3, uu[2][3]);
        #pragma unroll
        for (int off = 32; off >= 1; off >>= 1) {
            p0 += __shfl_xor(p0, off);
            p1 += __shfl_xor(p1, off);
            p2 += __shfl_xor(p2, off);
        }
        if (lane == 0) {
            const int row = wrow0 + i;
            d0[row] = p0; d1[row] = p1; d2[row] = p2;
        }
    }
}

// ---- k2: per (b, span, third): softmax stats + exp-weighted row accumulation.
// ybar partials in registers (3 x f32x4 per thread, thread owns k=tid*4..+4).
__global__ __launch_bounds__(256)
void span_acc_kernel(const float* __restrict__ X, const float* __restrict__ d0,
                     const float* __restrict__ d1, const float* __restrict__ d2,
                     const int* __restrict__ offs, float* __restrict__ part,
                     float* __restrict__ Zout) {
    __shared__ float lg[L_];
    __shared__ float red[4];
    const int blk = blockIdx.x;                          // 1152
    const int b   = blk / 9;
    const int r9  = blk - b * 9;
    const int s   = r9 / 3;
    const int sub = r9 - s * 3;
    const int tid = threadIdx.x, lane = tid & 63, wv = tid >> 6;
    const int st = offs[b * 6 + s * 2], en = offs[b * 6 + s * 2 + 1]; // inclusive
    const size_t g512 = (size_t)b * 512;

    // logits (softmax-shift-invariant form; constants dropped)
    for (int l = tid; l < L_; l += 256) {
        float v = d1[g512 + l];
        if (l >= 1)        v += d0[g512 + l - 1];
        if (l <= L_ - 2)   v += d2[g512 + l + 1];
        lg[l] = v;
    }
    __syncthreads();

    float mx = -1e30f;
    for (int l = st + tid; l <= en; l += 256) mx = fmaxf(mx, lg[l]);
    #pragma unroll
    for (int off = 32; off >= 1; off >>= 1) mx = fmaxf(mx, __shfl_xor(mx, off));
    if (lane == 0) red[wv] = mx;
    __syncthreads();
    mx = fmaxf(fmaxf(red[0], red[1]), fmaxf(red[2], red[3]));
    __syncthreads();

    float sm = 0.f;
    for (int l = st + tid; l <= en; l += 256) sm += __expf(lg[l] - mx);
    #pragma unroll
    for (int off = 32; off >= 1; off >>= 1) sm += __shfl_xor(sm, off);
    if (lane == 0) red[wv] = sm;
    __syncthreads();
    if (sub == 0 && tid == 0) Zout[b * 3 + s] = red[0] + red[1] + red[2] + red[3];

    // rows contributing: m in [st-1, en+1] clamped; this block takes third `sub`
    const int lo = max(st - 1, 0), hi = min(en + 1, L_ - 1);
    const int n   = hi - lo + 1;
    const int per = (n + 2) / 3;
    const int rlo = lo + sub * per;
    const int rhi = min(hi, rlo + per - 1);

    f32x4 acc[3] = {{0,0,0,0},{0,0,0,0},{0,0,0,0}};
    const float* Xb = X + g512 * 1024 + tid * 4;

    for (int m = rlo; m <= rhi; m += 2) {
        const int  m2   = min(m + 1, rhi);
        const bool has2 = (m + 1 <= rhi);
        f32x4 x0 = *(const f32x4*)(Xb + (size_t)m  * 1024);
        f32x4 x1 = *(const f32x4*)(Xb + (size_t)m2 * 1024);
        float al0[3], al1[3];
        #pragma unroll
        for (int t = 0; t < 3; ++t) {
            const int la = m + 1 - t,  lb = m + 2 - t;
            const int lac = min(max(la, 0), L_ - 1);
            const int lbc = min(max(lb, 0), L_ - 1);
            al0[t] = (la >= st && la <= en) ? __expf(lg[lac] - mx) : 0.f;
            al1[t] = (has2 && lb >= st && lb <= en) ? __expf(lg[lbc] - mx) : 0.f;
        }
        #pragma unroll
        for (int t = 0; t < 3; ++t) {
            acc[t] += al0[t] * x0;
            acc[t] += al1[t] * x1;
        }
    }

    float* pb = part + ((size_t)((b * 3 + s) * 3 + sub) * 3) * 1024 + tid * 4;
    *(f32x4*)(pb)        = acc[0];
    *(f32x4*)(pb + 1024) = acc[1];
    *(f32x4*)(pb + 2048) = acc[2];
}

// ---- k3: per batch: reduce partials -> ybar; e[s,o] = dot/Z + cb; BN1 -> fc
// -> ReLU -> BN2 -> concat -> last.
__global__ __launch_bounds__(256)
void head_kernel(const float* __restrict__ part, const float* __restrict__ Zv,
                 const float* __restrict__ Wt, const float* __restrict__ cb,
                 const float* __restrict__ in_urls, const float* __restrict__ other,
                 const float* __restrict__ bn1_g, const float* __restrict__ bn1_b,
                 const float* __restrict__ bn1_m, const float* __restrict__ bn1_v,
                 const float* __restrict__ fc_w, const float* __restrict__ fc_b,
                 const float* __restrict__ bn2_g, const float* __restrict__ bn2_b,
                 const float* __restrict__ bn2_m, const float* __restrict__ bn2_v,
                 const float* __restrict__ last_w, const float* __restrict__ last_b,
                 float* __restrict__ out) {
    __shared__ float yb[9 * 1024];       // 36 KB
    __shared__ float emb[NSPANS * 64];
    __shared__ float hbuf[HIDDEN];

    const int b = blockIdx.x, tid = threadIdx.x, lane = tid & 63, wv = tid >> 6;

    #pragma unroll
    for (int i = 0; i < 9; ++i) {        // i = s*3 + t
        const int s = i / 3, t = i - s * 3;
        const float* p = part + (size_t)(b * 27 + s * 9 + t) * 1024 + tid * 4;
        f32x4 v = *(const f32x4*)(p) + *(const f32x4*)(p + 3072) + *(const f32x4*)(p + 6144);
        *(f32x4*)(&yb[i * 1024 + tid * 4]) = v;
    }
    __syncthreads();

    if (tid < 192) {
        const int s = tid >> 6, o = tid & 63;
        float acc = 0.f;
        #pragma unroll
        for (int t = 0; t < 3; ++t) {
            const float* wp = Wt + (size_t)(t * 64 + o) * 1024;
            const float* yp = &yb[(s * 3 + t) * 1024];
            #pragma unroll 4
            for (int k = 0; k < 1024; k += 4) {
                f32x4 w = *(const f32x4*)(wp + k);
                f32x4 y = *(const f32x4*)(yp + k);
                acc += dp4(w, y);
            }
        }
        const float ev = acc / Zv[b * 3 + s] + cb[o];
        const int i = s * 64 + o;
        emb[i] = (ev - bn1_m[i]) * rsqrtf(bn1_v[i] + 1e-5f) * bn1_g[i] + bn1_b[i];
    }
    __syncthreads();

    #pragma unroll
    for (int q = 0; q < 2; ++q) {
        const int j = tid + q * 256;
        const float* wrow = fc_w + (size_t)j * (NSPANS * 64);
        float sacc = fc_b[j];
        #pragma unroll 8
        for (int i2 = 0; i2 < NSPANS * 64; ++i2) sacc += wrow[i2] * emb[i2];
        sacc = fmaxf(sacc, 0.f);
        hbuf[j] = (sacc - bn2_m[j]) * rsqrtf(bn2_v[j] + 1e-5f) * bn2_g[j] + bn2_b[j];
    }
    __syncthreads();

    if (wv < 3) {
        const float* lw = last_w + wv * (HIDDEN + 17);
        float s = 0.f;
        for (int i = lane; i < HIDDEN + 17; i += 64) {
            float f;
            if (i < HIDDEN)          f = hbuf[i];
            else if (i < HIDDEN + 3) f = in_urls[b * 3 + (i - HIDDEN)];
            else                     f = other[b * 14 + (i - HIDDEN - 3)];
            s += lw[i] * f;
        }
        #pragma unroll
        for (int off = 32; off >= 1; off >>= 1) s += __shfl_xor(s, off);
        if (lane == 0) out[b * 3 + wv] = s + last_b[wv];
    }
}

extern "C" void kernel_launch(void* const* d_in, const int* in_sizes, int n_in,
                              void* d_out, int out_size, void* d_ws, size_t ws_size,
                              hipStream_t stream) {
    const float* bert    = (const float*)d_in[0];
    const int*   offs    = (const int*)d_in[1];
    const float* in_urls = (const float*)d_in[2];
    const float* other   = (const float*)d_in[3];
    const float* conv_w  = (const float*)d_in[4];
    const float* conv_b  = (const float*)d_in[5];
    const float* att_w   = (const float*)d_in[6];
    // att_b (d_in[7]) cancels in the softmax shift — unused.
    const float* bn1_g   = (const float*)d_in[8];
    const float* bn1_b   = (const float*)d_in[9];
    const float* bn1_m   = (const float*)d_in[10];
    const float* bn1_v   = (const float*)d_in[11];
    const float* fc_w    = (const float*)d_in[12];
    const float* fc_b    = (const float*)d_in[13];
    const float* bn2_g   = (const float*)d_in[14];
    const float* bn2_b   = (const float*)d_in[15];
    const float* bn2_m   = (const float*)d_in[16];
    const float* bn2_v   = (const float*)d_in[17];
    const float* last_w  = (const float*)d_in[18];
    const float* last_b  = (const float*)d_in[19];

    // ws layout (bytes):
    //   u    @ 0        (12,288)
    //   Wt   @ 12,288   (786,432)
    //   d0   @ 798,720  (262,144)
    //   d1   @ 1,060,864 (262,144)
    //   d2   @ 1,323,008 (262,144)
    //   Z    @ 1,585,152 (1,536)
    //   part @ 1,586,688 (14,155,776)   total 15.74 MB
    float* u    = (float*)d_ws;
    float* Wt   = (float*)((char*)d_ws + 12288);
    float* d0   = (float*)((char*)d_ws + 798720);
    float* d1   = (float*)((char*)d_ws + 1060864);
    float* d2   = (float*)((char*)d_ws + 1323008);
    float* Zv   = (float*)((char*)d_ws + 1585152);
    float* part = (float*)((char*)d_ws + 1586688);

    hipLaunchKernelGGL(prep_kernel, dim3(96), dim3(256), 0, stream,
                       conv_w, att_w, u, Wt);
    hipLaunchKernelGGL(dots_kernel, dim3((B_ * L_) / 32), dim3(256), 0, stream,
                       bert, u, d0, d1, d2);
    hipLaunchKernelGGL(span_acc_kernel, dim3(B_ * NSPANS * 3), dim3(256), 0, stream,
                       bert, d0, d1, d2, offs, part, Zv);
    hipLaunchKernelGGL(head_kernel, dim3(B_), dim3(256), 0, stream,
                       part, Zv, Wt, conv_b, in_urls, other,
                       bn1_g, bn1_b, bn1_m, bn1_v, fc_w, fc_b,
                       bn2_g, bn2_b, bn2_m, bn2_v, last_w, last_b,
                       (float*)d_out);
}